// Round 5
// baseline (517.215 us; speedup 1.0000x reference)
//
#include <hip/hip_runtime.h>
#include <math.h>

#define NB   4
#define NN   4096
#define FIN  128
#define FOUT 128   // H*U
#define NH   4
#define UU   32

__device__ __forceinline__ unsigned short f2bf(float f) {
    unsigned u = __float_as_uint(f);
    u += 0x7fff + ((u >> 16) & 1);          // round-to-nearest-even
    return (unsigned short)(u >> 16);
}

// Lightweight workgroup barrier: LDS visibility only, global loads stay in flight.
// Safe here: k2 communicates between threads exclusively through LDS; the only
// global writes are the final out-stores which nothing in-kernel reads.
#define LBAR() asm volatile("s_waitcnt lgkmcnt(0)\n\ts_barrier" ::: "memory")

// ---------------- Kernel 1: hfeat(bf16) = x@W ; f1 = h·a_src ; f2 = h·a_dst ----------------
#define K1_ROWS 64
#define K1_RT   8
#define K1_CT   4
#define XPAD    132

__global__ __launch_bounds__(256) void k1_feat(
    const float* __restrict__ x, const float* __restrict__ W,
    const float* __restrict__ a_src, const float* __restrict__ a_dst,
    unsigned short* __restrict__ hbf, float* __restrict__ f1g, float* __restrict__ f2g)
{
    __shared__ __align__(16) float Wq[32 * FOUT];
    __shared__ __align__(16) float xs[K1_ROWS * XPAD];

    const int tid  = threadIdx.x;
    const int row0 = blockIdx.x * K1_ROWS;

    const float4* x4 = (const float4*)(x + (size_t)row0 * FIN);
    for (int idx = tid; idx < K1_ROWS * FIN / 4; idx += 256) {
        int r = idx >> 5, q = idx & 31;
        *(float4*)(xs + r * XPAD + q * 4) = x4[idx];
    }

    const int cg = tid & 31;
    const int rg = tid >> 5;
    float acc[K1_RT][K1_CT];
    #pragma unroll
    for (int rr = 0; rr < K1_RT; rr++)
        #pragma unroll
        for (int cc = 0; cc < K1_CT; cc++) acc[rr][cc] = 0.f;

    for (int kt = 0; kt < 4; kt++) {
        __syncthreads();
        for (int idx = tid; idx < 32 * FOUT / 4; idx += 256)
            ((float4*)Wq)[idx] = ((const float4*)W)[kt * 1024 + idx];
        __syncthreads();
        #pragma unroll
        for (int k4 = 0; k4 < 8; k4++) {
            const int kb = kt * 32 + k4 * 4;
            float4 xv[K1_RT];
            #pragma unroll
            for (int rr = 0; rr < K1_RT; rr++)
                xv[rr] = *(const float4*)(xs + (rg * K1_RT + rr) * XPAD + kb);
            #pragma unroll
            for (int kk = 0; kk < 4; kk++) {
                float wv[K1_CT];
                #pragma unroll
                for (int cc = 0; cc < K1_CT; cc++)
                    wv[cc] = Wq[(k4 * 4 + kk) * FOUT + cg + 32 * cc];
                #pragma unroll
                for (int rr = 0; rr < K1_RT; rr++) {
                    float xk = ((const float*)&xv[rr])[kk];
                    #pragma unroll
                    for (int cc = 0; cc < K1_CT; cc++)
                        acc[rr][cc] = fmaf(xk, wv[cc], acc[rr][cc]);
                }
            }
        }
    }
    __syncthreads();
    #pragma unroll
    for (int rr = 0; rr < K1_RT; rr++)
        #pragma unroll
        for (int cc = 0; cc < K1_CT; cc++)
            xs[(rg * K1_RT + rr) * XPAD + cg + 32 * cc] = acc[rr][cc];
    __syncthreads();

    unsigned short* hrow = hbf + (size_t)row0 * FOUT;
    for (int idx = tid; idx < K1_ROWS * FOUT / 8; idx += 256) {
        int r = idx >> 4, q = idx & 15;
        const float* src = xs + r * XPAD + q * 8;
        uint4 o;
        o.x = (unsigned)f2bf(src[0]) | ((unsigned)f2bf(src[1]) << 16);
        o.y = (unsigned)f2bf(src[2]) | ((unsigned)f2bf(src[3]) << 16);
        o.z = (unsigned)f2bf(src[4]) | ((unsigned)f2bf(src[5]) << 16);
        o.w = (unsigned)f2bf(src[6]) | ((unsigned)f2bf(src[7]) << 16);
        *(uint4*)(hrow + (size_t)r * FOUT + q * 8) = o;
    }

    for (int task = tid; task < K1_ROWS * NH * 2; task += 256) {
        int row = task >> 3;
        int head = (task >> 1) & 3;
        int which = task & 1;
        const float* av = which ? a_dst : a_src;
        float s = 0.f;
        #pragma unroll
        for (int u = 0; u < UU; u++)
            s += xs[row * XPAD + head * UU + u] * av[head * UU + u];
        float* dst = which ? f2g : f1g;
        dst[(size_t)(row0 + row) * NH + head] = s;
    }
}

// ---------------- Kernel 2: persistent sparse GAT, 8 rows/block, adj prefetch ----------------
#define CAP   512
#define PPART 132
#define RPB   8     // rows per block; grid = NB*NN/RPB = 2048 = 8 blocks/CU

__device__ __forceinline__ float lrelu(float e) { return e > 0.f ? e : 0.2f * e; }

__global__ __launch_bounds__(256, 8) void k2_gat(
    const float* __restrict__ adj, const unsigned short* __restrict__ hbf,
    const float* __restrict__ f1g, const float* __restrict__ f2g,
    const float* __restrict__ bias, float* __restrict__ out)
{
    // XCD-pair {2b,2b+1} serves batch b; consecutive blocks on an XCD stream adjacent adj rows.
    const int p    = blockIdx.x;
    const int xcd  = p & 7;
    const int b    = xcd >> 1;
    const int l    = ((p >> 3) << 1) | (p & 1);   // 0..511 within batch
    const int tid  = threadIdx.x;
    const int lane = tid & 63;
    const int wv   = tid >> 6;

    __shared__ int    nbr[CAP];
    __shared__ __align__(16) float4 alpha4[CAP];   // [k] -> e/exp for 4 heads
    __shared__ float  part[16][PPART];
    __shared__ __align__(16) float4 smax4[4];
    __shared__ float  wsum[16];                    // [wv*4+h]
    __shared__ int    wcnt[4];

    const float4* f2b = (const float4*)(f2g + (size_t)b * NN * NH);
    const unsigned short* hbase = hbf + (size_t)b * NN * FOUT;
    const unsigned long long below = (1ull << lane) - 1ull;

    // per-thread constants for phase C / epilogue
    const int cq = tid & 15, kg = tid >> 4, hh = cq >> 2;
    const unsigned short* hb = hbase + cq * 8;
    const float bias_r = (tid < FOUT) ? bias[tid] : 0.f;

    // ---- preload row t=0
    int i = l;
    float4 v[4], vn[4], f1v, f1n;
    {
        const float4* arow = (const float4*)(adj + (size_t)(b * NN + i) * NN);
        #pragma unroll
        for (int it = 0; it < 4; it++) v[it] = arow[wv * 256 + it * 64 + lane];
        f1v = ((const float4*)f1g)[b * NN + i];
    }

    for (int t = 0; t < RPB; t++) {
        const int row = b * NN + i;

        // ---- pass 1: count matches per wave (registers + ballots)
        int my_cnt = 0;
        #pragma unroll
        for (int it = 0; it < 4; it++) {
            const int jb = ((it * 4 + wv) * 64 + lane) << 2;   // NOTE: consistent with loads below
        }
        // (recompute with the real index mapping used for loads: idx4 = wv*256 + it*64 + lane)
        #pragma unroll
        for (int it = 0; it < 4; it++) {
            const int jb = (wv * 256 + it * 64 + lane) << 2;
            my_cnt += __popcll(__ballot((v[it].x > 0.f) | (jb + 0 == i)));
            my_cnt += __popcll(__ballot((v[it].y > 0.f) | (jb + 1 == i)));
            my_cnt += __popcll(__ballot((v[it].z > 0.f) | (jb + 2 == i)));
            my_cnt += __popcll(__ballot((v[it].w > 0.f) | (jb + 3 == i)));
        }
        if (lane == 0) wcnt[wv] = my_cnt;
        LBAR();

        const int w0 = wcnt[0], w1 = wcnt[1], w2 = wcnt[2], w3 = wcnt[3];
        int run = (wv > 0 ? w0 : 0) + (wv > 1 ? w1 : 0) + (wv > 2 ? w2 : 0);
        const int total = w0 + w1 + w2 + w3;
        const int K = (total < CAP) ? total : CAP;

        // ---- pass 2: write neighbor indices at deterministic slots
        #pragma unroll
        for (int it = 0; it < 4; it++) {
            const int jb = (wv * 256 + it * 64 + lane) << 2;
            const bool p0 = (v[it].x > 0.f) | (jb + 0 == i);
            const bool p1 = (v[it].y > 0.f) | (jb + 1 == i);
            const bool p2 = (v[it].z > 0.f) | (jb + 2 == i);
            const bool p3 = (v[it].w > 0.f) | (jb + 3 == i);
            unsigned long long m0 = __ballot(p0), m1 = __ballot(p1);
            unsigned long long m2 = __ballot(p2), m3 = __ballot(p3);
            int c0 = __popcll(m0), c1 = __popcll(m1), c2 = __popcll(m2), c3 = __popcll(m3);
            if (p0) { int s = run + __popcll(m0 & below);                if (s < CAP) nbr[s] = jb + 0; }
            if (p1) { int s = run + c0 + __popcll(m1 & below);           if (s < CAP) nbr[s] = jb + 1; }
            if (p2) { int s = run + c0 + c1 + __popcll(m2 & below);      if (s < CAP) nbr[s] = jb + 2; }
            if (p3) { int s = run + c0 + c1 + c2 + __popcll(m3 & below); if (s < CAP) nbr[s] = jb + 3; }
            run += c0 + c1 + c2 + c3;
        }

        // ---- prefetch next row's adj + f1 (in flight across the light barriers below)
        if (t + 1 < RPB) {
            const int inext = i + 512;
            const float4* arowN = (const float4*)(adj + (size_t)(b * NN + inext) * NN);
            #pragma unroll
            for (int it = 0; it < 4; it++) vn[it] = arowN[wv * 256 + it * 64 + lane];
            f1n = ((const float4*)f1g)[b * NN + inext];
        }
        LBAR();

        // ---- score phase: dense over k, one f2 gather in flight per thread; online max
        float4 hmax = make_float4(-1e30f, -1e30f, -1e30f, -1e30f);
        for (int k = tid; k < K; k += 256) {
            int j = nbr[k];
            float4 f2v = f2b[j];
            float4 e;
            e.x = lrelu(f1v.x + f2v.x);
            e.y = lrelu(f1v.y + f2v.y);
            e.z = lrelu(f1v.z + f2v.z);
            e.w = lrelu(f1v.w + f2v.w);
            alpha4[k] = e;
            hmax.x = fmaxf(hmax.x, e.x); hmax.y = fmaxf(hmax.y, e.y);
            hmax.z = fmaxf(hmax.z, e.z); hmax.w = fmaxf(hmax.w, e.w);
        }
        #pragma unroll
        for (int off = 32; off > 0; off >>= 1) {
            hmax.x = fmaxf(hmax.x, __shfl_xor(hmax.x, off, 64));
            hmax.y = fmaxf(hmax.y, __shfl_xor(hmax.y, off, 64));
            hmax.z = fmaxf(hmax.z, __shfl_xor(hmax.z, off, 64));
            hmax.w = fmaxf(hmax.w, __shfl_xor(hmax.w, off, 64));
        }
        if (lane == 0) smax4[wv] = hmax;
        LBAR();

        // ---- exp phase: normalize to exp(e - gmax), accumulate per-head sums
        float4 g0 = smax4[0], g1 = smax4[1], g2 = smax4[2], g3 = smax4[3];
        float4 gmax;
        gmax.x = fmaxf(fmaxf(g0.x, g1.x), fmaxf(g2.x, g3.x));
        gmax.y = fmaxf(fmaxf(g0.y, g1.y), fmaxf(g2.y, g3.y));
        gmax.z = fmaxf(fmaxf(g0.z, g1.z), fmaxf(g2.z, g3.z));
        gmax.w = fmaxf(fmaxf(g0.w, g1.w), fmaxf(g2.w, g3.w));
        float4 hsum = make_float4(0.f, 0.f, 0.f, 0.f);
        for (int k = tid; k < K; k += 256) {
            float4 e = alpha4[k];
            e.x = __expf(e.x - gmax.x);
            e.y = __expf(e.y - gmax.y);
            e.z = __expf(e.z - gmax.z);
            e.w = __expf(e.w - gmax.w);
            alpha4[k] = e;
            hsum.x += e.x; hsum.y += e.y; hsum.z += e.z; hsum.w += e.w;
        }
        #pragma unroll
        for (int off = 32; off > 0; off >>= 1) {
            hsum.x += __shfl_xor(hsum.x, off, 64);
            hsum.y += __shfl_xor(hsum.y, off, 64);
            hsum.z += __shfl_xor(hsum.z, off, 64);
            hsum.w += __shfl_xor(hsum.w, off, 64);
        }
        if (lane == 0) {
            wsum[wv * 4 + 0] = hsum.x; wsum[wv * 4 + 1] = hsum.y;
            wsum[wv * 4 + 2] = hsum.z; wsum[wv * 4 + 3] = hsum.w;
        }
        LBAR();

        // ---- phase C: bf16x8 gather per lane, 16-way k split, 2x unroll
        const float* alpf = (const float*)alpha4;
        float acc[8];
        #pragma unroll
        for (int u = 0; u < 8; u++) acc[u] = 0.f;
        int k = kg;
        for (; k + 16 < K; k += 32) {
            int j0 = nbr[k], j1 = nbr[k + 16];
            float a0 = alpf[k * 4 + hh], a1 = alpf[(k + 16) * 4 + hh];
            uint4 u4a = *(const uint4*)(hb + (size_t)j0 * FOUT);
            uint4 u4b = *(const uint4*)(hb + (size_t)j1 * FOUT);
            const unsigned* u0 = (const unsigned*)&u4a;
            const unsigned* u1 = (const unsigned*)&u4b;
            #pragma unroll
            for (int u = 0; u < 4; u++) {
                acc[2*u]   = fmaf(a0, __uint_as_float(u0[u] << 16),         acc[2*u]);
                acc[2*u+1] = fmaf(a0, __uint_as_float(u0[u] & 0xffff0000u), acc[2*u+1]);
            }
            #pragma unroll
            for (int u = 0; u < 4; u++) {
                acc[2*u]   = fmaf(a1, __uint_as_float(u1[u] << 16),         acc[2*u]);
                acc[2*u+1] = fmaf(a1, __uint_as_float(u1[u] & 0xffff0000u), acc[2*u+1]);
            }
        }
        if (k < K) {
            int j0 = nbr[k];
            float a0 = alpf[k * 4 + hh];
            uint4 u4a = *(const uint4*)(hb + (size_t)j0 * FOUT);
            const unsigned* u0 = (const unsigned*)&u4a;
            #pragma unroll
            for (int u = 0; u < 4; u++) {
                acc[2*u]   = fmaf(a0, __uint_as_float(u0[u] << 16),         acc[2*u]);
                acc[2*u+1] = fmaf(a0, __uint_as_float(u0[u] & 0xffff0000u), acc[2*u+1]);
            }
        }
        *(float4*)&part[kg][cq * 8]     = *(float4*)&acc[0];
        *(float4*)&part[kg][cq * 8 + 4] = *(float4*)&acc[4];
        LBAR();

        // ---- epilogue
        if (tid < FOUT) {
            const int h = tid >> 5;
            float s = wsum[h] + wsum[4 + h] + wsum[8 + h] + wsum[12 + h];
            float o = 0.f;
            #pragma unroll
            for (int g = 0; g < 16; g++) o += part[g][tid];
            o = o / s + bias_r;
            o = o > 0.f ? o : expm1f(o);
            out[(size_t)row * FOUT + tid] = o;
        }
        LBAR();   // protect nbr/alpha4/wcnt for next row against stragglers in epilogue reads

        if (t + 1 < RPB) {
            #pragma unroll
            for (int it = 0; it < 4; it++) v[it] = vn[it];
            f1v = f1n;
            i += 512;
        }
    }
}

extern "C" void kernel_launch(void* const* d_in, const int* in_sizes, int n_in,
                              void* d_out, int out_size, void* d_ws, size_t ws_size,
                              hipStream_t stream) {
    const float* x     = (const float*)d_in[0];
    const float* adj   = (const float*)d_in[1];
    const float* W     = (const float*)d_in[2];
    const float* a_src = (const float*)d_in[3];
    const float* a_dst = (const float*)d_in[4];
    const float* bias  = (const float*)d_in[5];
    float* out = (float*)d_out;

    char* ws = (char*)d_ws;
    unsigned short* hbf = (unsigned short*)ws;                        // 4 MB bf16
    float* f1g = (float*)(ws + (size_t)NB * NN * FOUT * 2);           // 256 KB
    float* f2g = f1g + (size_t)NB * NN * NH;                          // 256 KB

    k1_feat<<<NB * NN / K1_ROWS, 256, 0, stream>>>(x, W, a_src, a_dst, hbf, f1g, f2g);
    k2_gat<<<NB * NN / RPB, 256, 0, stream>>>(adj, hbf, f1g, f2g, bias, out);
}

// Round 6
// 437.431 us; speedup vs baseline: 1.1824x; 1.1824x over previous
//
#include <hip/hip_runtime.h>
#include <math.h>

#define NB   4
#define NN   4096
#define FIN  128
#define FOUT 128   // H*U
#define NH   4
#define UU   32

__device__ __forceinline__ unsigned short f2bf(float f) {
    unsigned u = __float_as_uint(f);
    u += 0x7fff + ((u >> 16) & 1);          // round-to-nearest-even
    return (unsigned short)(u >> 16);
}

// Lightweight workgroup barrier: LDS visibility only, global loads stay in flight.
// Safe here: k2 communicates between threads exclusively through LDS; the only
// global writes are the final out-stores which nothing in-kernel reads.
#define LBAR() asm volatile("s_waitcnt lgkmcnt(0)\n\ts_barrier" ::: "memory")

// ---------------- Kernel 1: hfeat(bf16) = x@W ; f1 = h·a_src ; f2 = h·a_dst ----------------
#define K1_ROWS 64
#define K1_RT   8
#define K1_CT   4
#define XPAD    132

__global__ __launch_bounds__(256) void k1_feat(
    const float* __restrict__ x, const float* __restrict__ W,
    const float* __restrict__ a_src, const float* __restrict__ a_dst,
    unsigned short* __restrict__ hbf, float* __restrict__ f1g, float* __restrict__ f2g)
{
    __shared__ __align__(16) float Wq[32 * FOUT];
    __shared__ __align__(16) float xs[K1_ROWS * XPAD];

    const int tid  = threadIdx.x;
    const int row0 = blockIdx.x * K1_ROWS;

    const float4* x4 = (const float4*)(x + (size_t)row0 * FIN);
    for (int idx = tid; idx < K1_ROWS * FIN / 4; idx += 256) {
        int r = idx >> 5, q = idx & 31;
        *(float4*)(xs + r * XPAD + q * 4) = x4[idx];
    }

    const int cg = tid & 31;
    const int rg = tid >> 5;
    float acc[K1_RT][K1_CT];
    #pragma unroll
    for (int rr = 0; rr < K1_RT; rr++)
        #pragma unroll
        for (int cc = 0; cc < K1_CT; cc++) acc[rr][cc] = 0.f;

    for (int kt = 0; kt < 4; kt++) {
        __syncthreads();
        for (int idx = tid; idx < 32 * FOUT / 4; idx += 256)
            ((float4*)Wq)[idx] = ((const float4*)W)[kt * 1024 + idx];
        __syncthreads();
        #pragma unroll
        for (int k4 = 0; k4 < 8; k4++) {
            const int kb = kt * 32 + k4 * 4;
            float4 xv[K1_RT];
            #pragma unroll
            for (int rr = 0; rr < K1_RT; rr++)
                xv[rr] = *(const float4*)(xs + (rg * K1_RT + rr) * XPAD + kb);
            #pragma unroll
            for (int kk = 0; kk < 4; kk++) {
                float wv[K1_CT];
                #pragma unroll
                for (int cc = 0; cc < K1_CT; cc++)
                    wv[cc] = Wq[(k4 * 4 + kk) * FOUT + cg + 32 * cc];
                #pragma unroll
                for (int rr = 0; rr < K1_RT; rr++) {
                    float xk = ((const float*)&xv[rr])[kk];
                    #pragma unroll
                    for (int cc = 0; cc < K1_CT; cc++)
                        acc[rr][cc] = fmaf(xk, wv[cc], acc[rr][cc]);
                }
            }
        }
    }
    __syncthreads();
    #pragma unroll
    for (int rr = 0; rr < K1_RT; rr++)
        #pragma unroll
        for (int cc = 0; cc < K1_CT; cc++)
            xs[(rg * K1_RT + rr) * XPAD + cg + 32 * cc] = acc[rr][cc];
    __syncthreads();

    unsigned short* hrow = hbf + (size_t)row0 * FOUT;
    for (int idx = tid; idx < K1_ROWS * FOUT / 8; idx += 256) {
        int r = idx >> 4, q = idx & 15;
        const float* src = xs + r * XPAD + q * 8;
        uint4 o;
        o.x = (unsigned)f2bf(src[0]) | ((unsigned)f2bf(src[1]) << 16);
        o.y = (unsigned)f2bf(src[2]) | ((unsigned)f2bf(src[3]) << 16);
        o.z = (unsigned)f2bf(src[4]) | ((unsigned)f2bf(src[5]) << 16);
        o.w = (unsigned)f2bf(src[6]) | ((unsigned)f2bf(src[7]) << 16);
        *(uint4*)(hrow + (size_t)r * FOUT + q * 8) = o;
    }

    for (int task = tid; task < K1_ROWS * NH * 2; task += 256) {
        int row = task >> 3;
        int head = (task >> 1) & 3;
        int which = task & 1;
        const float* av = which ? a_dst : a_src;
        float s = 0.f;
        #pragma unroll
        for (int u = 0; u < UU; u++)
            s += xs[row * XPAD + head * UU + u] * av[head * UU + u];
        float* dst = which ? f2g : f1g;
        dst[(size_t)(row0 + row) * NH + head] = s;
    }
}

// ---------------- Kernel 2: persistent sparse GAT, 8 rows/block, adj prefetch ----------------
// __launch_bounds__(256,4): VGPR cap 128. (256,8) capped VGPRs at 32 -> scratch
// spills -> 222 MB of spurious HBM writes (R5 post-mortem). Do not raise past 4
// without checking -Rpass-analysis=kernel-resource-usage.
#define CAP   512
#define PPART 132
#define RPB   8     // rows per block; grid = NB*NN/RPB = 2048

__device__ __forceinline__ float lrelu(float e) { return e > 0.f ? e : 0.2f * e; }

__global__ __launch_bounds__(256, 4) void k2_gat(
    const float* __restrict__ adj, const unsigned short* __restrict__ hbf,
    const float* __restrict__ f1g, const float* __restrict__ f2g,
    const float* __restrict__ bias, float* __restrict__ out)
{
    // XCD-pair {2b,2b+1} serves batch b; consecutive blocks on an XCD stream adjacent adj rows.
    const int p    = blockIdx.x;
    const int xcd  = p & 7;
    const int b    = xcd >> 1;
    const int l    = ((p >> 3) << 1) | (p & 1);   // 0..511 within batch
    const int tid  = threadIdx.x;
    const int lane = tid & 63;
    const int wv   = tid >> 6;

    __shared__ int    nbr[CAP];
    __shared__ __align__(16) float4 alpha4[CAP];   // [k] -> e/exp for 4 heads
    __shared__ float  part[16][PPART];
    __shared__ __align__(16) float4 smax4[4];
    __shared__ float  wsum[16];                    // [wv*4+h]
    __shared__ int    wcnt[4];

    const float4* f2b = (const float4*)(f2g + (size_t)b * NN * NH);
    const unsigned short* hbase = hbf + (size_t)b * NN * FOUT;
    const unsigned long long below = (1ull << lane) - 1ull;

    const int cq = tid & 15, kg = tid >> 4, hh = cq >> 2;
    const unsigned short* hb = hbase + cq * 8;
    const float bias_r = (tid < FOUT) ? bias[tid] : 0.f;

    // ---- preload row t=0
    int i = l;
    float4 v[4], vn[4], f1v, f1n;
    {
        const float4* arow = (const float4*)(adj + (size_t)(b * NN + i) * NN);
        #pragma unroll
        for (int it = 0; it < 4; it++) v[it] = arow[wv * 256 + it * 64 + lane];
        f1v = ((const float4*)f1g)[b * NN + i];
    }

    for (int t = 0; t < RPB; t++) {
        const int row = b * NN + i;

        // ---- pass 1: count matches per wave (registers + ballots)
        int my_cnt = 0;
        #pragma unroll
        for (int it = 0; it < 4; it++) {
            const int jb = (wv * 256 + it * 64 + lane) << 2;
            my_cnt += __popcll(__ballot((v[it].x > 0.f) | (jb + 0 == i)));
            my_cnt += __popcll(__ballot((v[it].y > 0.f) | (jb + 1 == i)));
            my_cnt += __popcll(__ballot((v[it].z > 0.f) | (jb + 2 == i)));
            my_cnt += __popcll(__ballot((v[it].w > 0.f) | (jb + 3 == i)));
        }
        if (lane == 0) wcnt[wv] = my_cnt;
        LBAR();

        const int w0 = wcnt[0], w1 = wcnt[1], w2 = wcnt[2], w3 = wcnt[3];
        int run = (wv > 0 ? w0 : 0) + (wv > 1 ? w1 : 0) + (wv > 2 ? w2 : 0);
        const int total = w0 + w1 + w2 + w3;
        const int K = (total < CAP) ? total : CAP;

        // ---- pass 2: write neighbor indices at deterministic slots
        #pragma unroll
        for (int it = 0; it < 4; it++) {
            const int jb = (wv * 256 + it * 64 + lane) << 2;
            const bool p0 = (v[it].x > 0.f) | (jb + 0 == i);
            const bool p1 = (v[it].y > 0.f) | (jb + 1 == i);
            const bool p2 = (v[it].z > 0.f) | (jb + 2 == i);
            const bool p3 = (v[it].w > 0.f) | (jb + 3 == i);
            unsigned long long m0 = __ballot(p0), m1 = __ballot(p1);
            unsigned long long m2 = __ballot(p2), m3 = __ballot(p3);
            int c0 = __popcll(m0), c1 = __popcll(m1), c2 = __popcll(m2), c3 = __popcll(m3);
            if (p0) { int s = run + __popcll(m0 & below);                if (s < CAP) nbr[s] = jb + 0; }
            if (p1) { int s = run + c0 + __popcll(m1 & below);           if (s < CAP) nbr[s] = jb + 1; }
            if (p2) { int s = run + c0 + c1 + __popcll(m2 & below);      if (s < CAP) nbr[s] = jb + 2; }
            if (p3) { int s = run + c0 + c1 + c2 + __popcll(m3 & below); if (s < CAP) nbr[s] = jb + 3; }
            run += c0 + c1 + c2 + c3;
        }

        // ---- prefetch next row's adj + f1 (stays in flight across the light barriers)
        if (t + 1 < RPB) {
            const int inext = i + 512;
            const float4* arowN = (const float4*)(adj + (size_t)(b * NN + inext) * NN);
            #pragma unroll
            for (int it = 0; it < 4; it++) vn[it] = arowN[wv * 256 + it * 64 + lane];
            f1n = ((const float4*)f1g)[b * NN + inext];
        }
        LBAR();

        // ---- score phase: dense over k, one f2 gather per thread; online max
        float4 hmax = make_float4(-1e30f, -1e30f, -1e30f, -1e30f);
        for (int k = tid; k < K; k += 256) {
            int j = nbr[k];
            float4 f2v = f2b[j];
            float4 e;
            e.x = lrelu(f1v.x + f2v.x);
            e.y = lrelu(f1v.y + f2v.y);
            e.z = lrelu(f1v.z + f2v.z);
            e.w = lrelu(f1v.w + f2v.w);
            alpha4[k] = e;
            hmax.x = fmaxf(hmax.x, e.x); hmax.y = fmaxf(hmax.y, e.y);
            hmax.z = fmaxf(hmax.z, e.z); hmax.w = fmaxf(hmax.w, e.w);
        }
        #pragma unroll
        for (int off = 32; off > 0; off >>= 1) {
            hmax.x = fmaxf(hmax.x, __shfl_xor(hmax.x, off, 64));
            hmax.y = fmaxf(hmax.y, __shfl_xor(hmax.y, off, 64));
            hmax.z = fmaxf(hmax.z, __shfl_xor(hmax.z, off, 64));
            hmax.w = fmaxf(hmax.w, __shfl_xor(hmax.w, off, 64));
        }
        if (lane == 0) smax4[wv] = hmax;
        LBAR();

        // ---- exp phase: exp(e - gmax), per-head sums
        float4 g0 = smax4[0], g1 = smax4[1], g2 = smax4[2], g3 = smax4[3];
        float4 gmax;
        gmax.x = fmaxf(fmaxf(g0.x, g1.x), fmaxf(g2.x, g3.x));
        gmax.y = fmaxf(fmaxf(g0.y, g1.y), fmaxf(g2.y, g3.y));
        gmax.z = fmaxf(fmaxf(g0.z, g1.z), fmaxf(g2.z, g3.z));
        gmax.w = fmaxf(fmaxf(g0.w, g1.w), fmaxf(g2.w, g3.w));
        float4 hsum = make_float4(0.f, 0.f, 0.f, 0.f);
        for (int k = tid; k < K; k += 256) {
            float4 e = alpha4[k];
            e.x = __expf(e.x - gmax.x);
            e.y = __expf(e.y - gmax.y);
            e.z = __expf(e.z - gmax.z);
            e.w = __expf(e.w - gmax.w);
            alpha4[k] = e;
            hsum.x += e.x; hsum.y += e.y; hsum.z += e.z; hsum.w += e.w;
        }
        #pragma unroll
        for (int off = 32; off > 0; off >>= 1) {
            hsum.x += __shfl_xor(hsum.x, off, 64);
            hsum.y += __shfl_xor(hsum.y, off, 64);
            hsum.z += __shfl_xor(hsum.z, off, 64);
            hsum.w += __shfl_xor(hsum.w, off, 64);
        }
        if (lane == 0) {
            wsum[wv * 4 + 0] = hsum.x; wsum[wv * 4 + 1] = hsum.y;
            wsum[wv * 4 + 2] = hsum.z; wsum[wv * 4 + 3] = hsum.w;
        }
        LBAR();

        // ---- phase C: bf16x8 gather per lane, 16-way k split, 2x unroll
        const float* alpf = (const float*)alpha4;
        float acc[8];
        #pragma unroll
        for (int u = 0; u < 8; u++) acc[u] = 0.f;
        int k = kg;
        for (; k + 16 < K; k += 32) {
            int j0 = nbr[k], j1 = nbr[k + 16];
            float a0 = alpf[k * 4 + hh], a1 = alpf[(k + 16) * 4 + hh];
            uint4 u4a = *(const uint4*)(hb + (size_t)j0 * FOUT);
            uint4 u4b = *(const uint4*)(hb + (size_t)j1 * FOUT);
            const unsigned* u0 = (const unsigned*)&u4a;
            const unsigned* u1 = (const unsigned*)&u4b;
            #pragma unroll
            for (int u = 0; u < 4; u++) {
                acc[2*u]   = fmaf(a0, __uint_as_float(u0[u] << 16),         acc[2*u]);
                acc[2*u+1] = fmaf(a0, __uint_as_float(u0[u] & 0xffff0000u), acc[2*u+1]);
            }
            #pragma unroll
            for (int u = 0; u < 4; u++) {
                acc[2*u]   = fmaf(a1, __uint_as_float(u1[u] << 16),         acc[2*u]);
                acc[2*u+1] = fmaf(a1, __uint_as_float(u1[u] & 0xffff0000u), acc[2*u+1]);
            }
        }
        if (k < K) {
            int j0 = nbr[k];
            float a0 = alpf[k * 4 + hh];
            uint4 u4a = *(const uint4*)(hb + (size_t)j0 * FOUT);
            const unsigned* u0 = (const unsigned*)&u4a;
            #pragma unroll
            for (int u = 0; u < 4; u++) {
                acc[2*u]   = fmaf(a0, __uint_as_float(u0[u] << 16),         acc[2*u]);
                acc[2*u+1] = fmaf(a0, __uint_as_float(u0[u] & 0xffff0000u), acc[2*u+1]);
            }
        }
        *(float4*)&part[kg][cq * 8]     = *(float4*)&acc[0];
        *(float4*)&part[kg][cq * 8 + 4] = *(float4*)&acc[4];
        LBAR();

        // ---- epilogue
        if (tid < FOUT) {
            const int h = tid >> 5;
            float s = wsum[h] + wsum[4 + h] + wsum[8 + h] + wsum[12 + h];
            float o = 0.f;
            #pragma unroll
            for (int g = 0; g < 16; g++) o += part[g][tid];
            o = o / s + bias_r;
            o = o > 0.f ? o : expm1f(o);
            out[(size_t)row * FOUT + tid] = o;
        }
        LBAR();   // protect nbr/alpha4/wcnt for next row

        if (t + 1 < RPB) {
            #pragma unroll
            for (int it = 0; it < 4; it++) v[it] = vn[it];
            f1v = f1n;
            i += 512;
        }
    }
}

extern "C" void kernel_launch(void* const* d_in, const int* in_sizes, int n_in,
                              void* d_out, int out_size, void* d_ws, size_t ws_size,
                              hipStream_t stream) {
    const float* x     = (const float*)d_in[0];
    const float* adj   = (const float*)d_in[1];
    const float* W     = (const float*)d_in[2];
    const float* a_src = (const float*)d_in[3];
    const float* a_dst = (const float*)d_in[4];
    const float* bias  = (const float*)d_in[5];
    float* out = (float*)d_out;

    char* ws = (char*)d_ws;
    unsigned short* hbf = (unsigned short*)ws;                        // 4 MB bf16
    float* f1g = (float*)(ws + (size_t)NB * NN * FOUT * 2);           // 256 KB
    float* f2g = f1g + (size_t)NB * NN * NH;                          // 256 KB

    k1_feat<<<NB * NN / K1_ROWS, 256, 0, stream>>>(x, W, a_src, a_dst, hbf, f1g, f2g);
    k2_gat<<<NB * NN / RPB, 256, 0, stream>>>(adj, hbf, f1g, f2g, bias, out);
}